// Round 9
// baseline (221.482 us; speedup 1.0000x reference)
//
#include <hip/hip_runtime.h>
#include <hip/hip_bf16.h>

typedef __hip_bfloat16 bf16;
typedef __attribute__((ext_vector_type(4))) float f32x4;
typedef __attribute__((ext_vector_type(8))) short s16x8;
typedef __attribute__((ext_vector_type(4))) short s16x4;

__device__ __forceinline__ void gld_lds16(const void* g, void* l) {
  __builtin_amdgcn_global_load_lds(
      (const __attribute__((address_space(1))) unsigned int*)g,
      (__attribute__((address_space(3))) unsigned int*)l, 16, 0, 0);
}

__device__ __forceinline__ short bf16bits(float f) {
  bf16 h = __float2bfloat16(f);
  return *reinterpret_cast<short*>(&h);
}

__device__ __forceinline__ int psw(int row) {
  return ((row & 7) << 4) ^ ((row & 8) << 2);
}

// K/V weight-column permutation: n=(h,d) -> r*128 + (h>>3)*64 + d, r=h&7
__device__ __forceinline__ int kvperm(int n) {
  return ((n >> 6) & 7) * 128 + (n >> 9) * 64 + (n & 63);
}

// ---------------- f32 -> bf16 elementwise convert ----------------
__global__ __launch_bounds__(256) void cvt_f32_bf16(const float* __restrict__ in,
                                                    bf16* __restrict__ out, int n) {
  int i = (blockIdx.x * 256 + threadIdx.x) * 4;
  if (i + 3 < n) {
    float4 v = *reinterpret_cast<const float4*>(in + i);
    s16x4 o;
    o[0] = bf16bits(v.x); o[1] = bf16bits(v.y);
    o[2] = bf16bits(v.z); o[3] = bf16bits(v.w);
    *reinterpret_cast<s16x4*>(out + i) = o;
  }
}

// ---------------- W (KxN f32) -> Wt (perm(N) x K bf16) ----------------
template <int PERM>
__global__ __launch_bounds__(256) void transpose_cvt(const float* __restrict__ W,
                                                     bf16* __restrict__ Wt, int K, int N,
                                                     int rowofs) {
  __shared__ float tile[32][33];
  int k0 = blockIdx.x * 32, n0 = blockIdx.y * 32;
  int tx = threadIdx.x, ty = threadIdx.y;  // block (32,8)
  for (int i = ty; i < 32; i += 8) tile[i][tx] = W[(size_t)(k0 + i) * N + n0 + tx];
  __syncthreads();
  for (int i = ty; i < 32; i += 8) {
    int nn = n0 + i;
    int orow = rowofs + (PERM ? kvperm(nn) : nn);
    Wt[(size_t)orow * K + k0 + tx] = __float2bfloat16(tile[tx][i]);
  }
}

// ---------------- bias concat (permuted for K/V groups) ----------------
__global__ __launch_bounds__(256) void bias_concat(const float* __restrict__ bq,
                                                   const float* __restrict__ bk,
                                                   const float* __restrict__ bv,
                                                   float* __restrict__ ob) {
  int n = blockIdx.x * 256 + threadIdx.x;
  if (n < 1024) {
    ob[n] = bq[n];
    int pr = kvperm(n);
    ob[1024 + pr] = bk[n];
    ob[2048 + pr] = bv[n];
  }
}

// ---------------- mask scan: pos/srcrow/cnt per pattern ----------------
__global__ __launch_bounds__(64) void mask_scan(const int* __restrict__ mask,
                                                int* __restrict__ pos_tab,
                                                int* __restrict__ srcrow,
                                                int* __restrict__ cnt) {
  int r = blockIdx.x;
  const int* mr = mask + r * 1024;
  int lane = threadIdx.x;
  int loc[16];
  int c = 0;
#pragma unroll
  for (int i = 0; i < 16; i++) {
    loc[i] = (mr[lane * 16 + i] == 0) ? 1 : 0;
    c += loc[i];
  }
  int inc = c;
#pragma unroll
  for (int off = 1; off < 64; off <<= 1) {
    int v = __shfl_up(inc, off);
    if (lane >= off) inc += v;
  }
  int running = inc - c;
#pragma unroll
  for (int i = 0; i < 16; i++) {
    pos_tab[r * 1024 + lane * 16 + i] = loc[i] ? running : -1;
    if (loc[i]) srcrow[r * 1024 + running] = lane * 16 + i;
    running += loc[i];
  }
  if (lane == 63) cnt[r] = inc;
}

// ---------------- zero-fill compacted tails [cnt, round64(cnt)) ----------------
__global__ __launch_bounds__(256) void tail_zero(bf16* __restrict__ kc,
                                                 bf16* __restrict__ vTc,
                                                 const int* __restrict__ cnt) {
  int bh = blockIdx.x;
  int c = cnt[bh & 7];
  int e = (c + 63) & ~63;
  int tid = threadIdx.x;
  bf16 z = __float2bfloat16(0.f);
  bf16* kb = kc + (size_t)bh * 1024 * 128;
  for (int i = tid; i < 64 * 128; i += 256) {
    int rr = c + (i >> 7);
    if (rr < e) kb[(size_t)rr * 128 + (i & 127)] = z;
  }
  bf16* vb = vTc + (size_t)bh * 64 * 1024;
  for (int i = tid; i < 64 * 64; i += 256) {
    int dv = i >> 6, col = c + (i & 63);
    if (col < e) vb[(size_t)dv * 1024 + col] = z;
  }
}

// ---------------- merged QKV GEMM (3-deep pipeline + L2-chunked dispatch) ----------------
// 1-D grid 1536. xcd = id&7, seq = id>>3 (per-XCD order):
//   seq<64  -> Q chunk: 8 A-tiles x 8 B-tiles L2-resident per XCD.
//              bx = xcd*8 + (seq&7), nt = seq>>3.
//   seq>=64 -> K/V chunks of 16 blocks with FIXED (b,r): gather set (~1MB)
//              + 2 B-tiles L2-resident; (g,mt) vary inside the chunk so the
//              exit-prone mt stays XCD-balanced (R5 fix preserved).
__global__ __launch_bounds__(256) void gemm_qkv(
    const bf16* __restrict__ A, const bf16* __restrict__ Bt,
    const float* __restrict__ bias, const int* __restrict__ srcrow,
    const int* __restrict__ cnt_g,
    bf16* __restrict__ qcat, bf16* __restrict__ kc, bf16* __restrict__ vTc) {
  __shared__ bf16 Alds[3][128 * 32];
  __shared__ bf16 Blds[3][128 * 32];
  const int id = blockIdx.x;
  const int xcd = id & 7;
  const int seq = id >> 3;

  int nt, bx;
  if (seq < 64) {
    nt = seq >> 3;                    // Q tile column 0..7
    bx = xcd * 8 + (seq & 7);         // Q row-tile 0..63
  } else {
    int s2 = seq - 64;
    int chunkid = xcd * 8 + (s2 >> 4);   // 0..63 -> (b, r)
    int w = s2 & 15;                     // (g, mt)
    int bq_ = chunkid & 7;
    int rq = chunkid >> 3;
    int gq = 1 + (w >> 3);
    int mt = w & 7;
    nt = gq * 8 + rq;
    bx = mt * 8 + bq_;                   // downstream decode: b=bx&7, basep=(bx>>3)*128
  }

  const int g = nt >> 3;
  const int n0 = nt * 128;
  const int r = nt & 7;
  const int tid = threadIdx.x;
  const int lane = tid & 63, wv = tid >> 6;
  const int wm = wv >> 1, wn = wv & 1;
  const int rlo = lane & 15, kgp = lane >> 4;
  const int srow = tid >> 2, ssl = tid & 3;

  int mrow0, mrow1, b = 0, basep = 0, vcnt = 128;
  if (g == 0) {
    int bm = bx * 128;
    mrow0 = bm + srow;
    mrow1 = bm + 64 + srow;
  } else {
    b = bx & 7;
    basep = (bx >> 3) * 128;
    int cr = cnt_g[r];
    if (basep >= cr) return;
    vcnt = min(128, cr - basep);
    int p0 = min(basep + srow, cr - 1);
    int p1 = min(basep + 64 + srow, cr - 1);
    mrow0 = b * 1024 + srcrow[r * 1024 + p0];
    mrow1 = b * 1024 + srcrow[r * 1024 + p1];
  }

  f32x4 acc[4][4];
#pragma unroll
  for (int i = 0; i < 4; i++)
#pragma unroll
    for (int j = 0; j < 4; j++) acc[i][j] = (f32x4){0.f, 0.f, 0.f, 0.f};

  const int gslA = ssl ^ ((srow >> 1) & 3);  // same for srow and srow+64

  auto STAGE = [&](int buf, int kt) {
    char* Ad = (char*)Alds[buf];
    char* Bd = (char*)Blds[buf];
    gld_lds16(A + (size_t)mrow0 * 1024 + kt + gslA * 8, Ad + tid * 16);
    gld_lds16(A + (size_t)mrow1 * 1024 + kt + gslA * 8, Ad + (256 + tid) * 16);
    gld_lds16(Bt + (size_t)(n0 + srow) * 1024 + kt + gslA * 8, Bd + tid * 16);
    gld_lds16(Bt + (size_t)(n0 + 64 + srow) * 1024 + kt + gslA * 8, Bd + (256 + tid) * 16);
  };

  STAGE(0, 0);
  STAGE(1, 32);
  int cur = 0;
#pragma unroll 1
  for (int ti = 0; ti < 32; ti++) {
    if (ti < 31) {
      asm volatile("s_waitcnt vmcnt(4)" ::: "memory");   // tile ti done; ti+1 in flight
    } else {
      asm volatile("s_waitcnt vmcnt(0)" ::: "memory");   // final tile: full drain
    }
    __syncthreads();
    if (ti + 2 < 32) {
      int b2 = cur + 2;
      if (b2 >= 3) b2 -= 3;
      STAGE(b2, (ti + 2) * 32);
    }

    char* Ab = (char*)Alds[cur];
    char* Bb = (char*)Blds[cur];
    s16x8 afr[4], bfr[4];
#pragma unroll
    for (int mi = 0; mi < 4; mi++) {
      int row = wm * 64 + mi * 16 + rlo;
      int ps = kgp ^ ((row >> 1) & 3);
      afr[mi] = *(const s16x8*)(Ab + row * 64 + ps * 16);
    }
#pragma unroll
    for (int ni = 0; ni < 4; ni++) {
      int row = wn * 64 + ni * 16 + rlo;
      int ps = kgp ^ ((row >> 1) & 3);
      bfr[ni] = *(const s16x8*)(Bb + row * 64 + ps * 16);
    }
#pragma unroll
    for (int mi = 0; mi < 4; mi++)
#pragma unroll
      for (int ni = 0; ni < 4; ni++)
        acc[mi][ni] = __builtin_amdgcn_mfma_f32_16x16x32_bf16(afr[mi], bfr[ni], acc[mi][ni], 0, 0, 0);
    cur = (cur == 2) ? 0 : cur + 1;
  }

#pragma unroll
  for (int mi = 0; mi < 4; mi++) {
#pragma unroll
    for (int ni = 0; ni < 4; ni++) {
      int nl = wn * 64 + ni * 16 + rlo;
      float bv = bias[n0 + nl];
#pragma unroll
      for (int reg = 0; reg < 4; reg++) {
        int ml = wm * 64 + mi * 16 + kgp * 4 + reg;
        float v = acc[mi][ni][reg] + bv;
        v = v > 0.f ? v : 0.f;
        bf16 vb = __float2bfloat16(v);
        if (g == 0) {
          int m = bx * 128 + ml;
          int b0 = m >> 10, s = m & 1023;
          int hh = nl >> 6, d = nl & 63;
          qcat[((size_t)(b0 * 16 + hh) * 1024 + s) * 128 + d] = vb;
        } else {
          int hbit = nl >> 6, d = nl & 63;
          int hh = hbit * 8 + r;
          int p = basep + ml;
          if (ml < vcnt) {
            if (g == 1)
              kc[((size_t)(b * 16 + hh) * 1024 + p) * 128 + d] = vb;
            else
              vTc[((size_t)(b * 16 + hh) * 64 + d) * 1024 + p] = vb;
          }
        }
      }
    }
  }
}

// ---------------- generic GEMM (L-proj dual-write / O-reduce), 2-phase ----------------
// MODE 1 uses a 1-D grid (512) with the same L2 chunking: 8 A-tiles x 8 B-tiles/XCD.
template <int MODE>
__global__ __launch_bounds__(256) void gemm_bf16(
    const bf16* __restrict__ A, const bf16* __restrict__ Bt,
    const float* __restrict__ bias, int K, int lda, int ldb,
    bf16* dstq, bf16* dstk, int dofs, const int* __restrict__ pos_tab, float* out) {
  __shared__ bf16 Alds[2][128 * 32];
  __shared__ bf16 Blds[2][128 * 32];
  __shared__ int pos_l[2][128];
  const int tid = threadIdx.x;
  const int lane = tid & 63, wv = tid >> 6;
  const int wm = wv >> 1, wn = wv & 1;
  int bm, bn;
  if (MODE == 1) {
    int id = blockIdx.x, xcd = id & 7, seq = id >> 3;
    bm = (xcd * 8 + (seq & 7)) * 128;
    bn = (seq >> 3) * 128;
  } else {
    bm = blockIdx.x * 128;
    bn = blockIdx.y * 128;
  }
  const int rlo = lane & 15, kgp = lane >> 4;

  if (MODE == 0 && pos_tab) {
    int h0 = bn >> 6;
    int hs = tid >> 7, sl = tid & 127;
    pos_l[hs][sl] = pos_tab[((h0 + hs) & 7) * 1024 + (bm & 1023) + sl];
  }

  f32x4 acc[4][4];
#pragma unroll
  for (int i = 0; i < 4; i++)
#pragma unroll
    for (int j = 0; j < 4; j++) acc[i][j] = (f32x4){0.f, 0.f, 0.f, 0.f};

  const int srow = tid >> 2, ssl = tid & 3;

  auto STAGE = [&](int buf, int kt) {
    char* Ad = (char*)Alds[buf];
    char* Bd = (char*)Blds[buf];
#pragma unroll
    for (int rr = 0; rr < 2; ++rr) {
      int row = rr * 64 + srow;
      int gsl = ssl ^ ((row >> 1) & 3);
      gld_lds16(A + (size_t)(bm + row) * lda + kt + gsl * 8, Ad + (rr * 256 + tid) * 16);
      gld_lds16(Bt + (size_t)(bn + row) * ldb + kt + gsl * 8, Bd + (rr * 256 + tid) * 16);
    }
  };

  STAGE(0, 0);
  int cur = 0;
#pragma unroll 1
  for (int kt = 0; kt < K; kt += 32) {
    asm volatile("s_waitcnt vmcnt(0)" ::: "memory");
    __syncthreads();
    if (kt + 32 < K) STAGE(cur ^ 1, kt + 32);

    char* Ab = (char*)Alds[cur];
    char* Bb = (char*)Blds[cur];
    s16x8 afr[4], bfr[4];
#pragma unroll
    for (int mi = 0; mi < 4; mi++) {
      int row = wm * 64 + mi * 16 + rlo;
      int ps = kgp ^ ((row >> 1) & 3);
      afr[mi] = *(const s16x8*)(Ab + row * 64 + ps * 16);
    }
#pragma unroll
    for (int ni = 0; ni < 4; ni++) {
      int row = wn * 64 + ni * 16 + rlo;
      int ps = kgp ^ ((row >> 1) & 3);
      bfr[ni] = *(const s16x8*)(Bb + row * 64 + ps * 16);
    }
#pragma unroll
    for (int mi = 0; mi < 4; mi++)
#pragma unroll
      for (int ni = 0; ni < 4; ni++)
        acc[mi][ni] = __builtin_amdgcn_mfma_f32_16x16x32_bf16(afr[mi], bfr[ni], acc[mi][ni], 0, 0, 0);
    cur ^= 1;
  }

  if (MODE == 0) {
    const int b = bm >> 10;
#pragma unroll
    for (int mi = 0; mi < 4; mi++) {
#pragma unroll
      for (int ni = 0; ni < 4; ni++) {
        int nl = wn * 64 + ni * 16 + rlo;
        int n = bn + nl;
        float bv = bias[n];
        int hh = n >> 6, d = n & 63, hs = nl >> 6;
#pragma unroll
        for (int reg = 0; reg < 4; reg++) {
          int ml = wm * 64 + mi * 16 + kgp * 4 + reg;
          int s = (bm & 1023) + ml;
          float v = acc[mi][ni][reg] + bv;
          v = v > 0.f ? v : 0.f;
          bf16 vb = __float2bfloat16(v);
          size_t hbase = (size_t)(b * 16 + hh) * 1024;
          dstq[(hbase + s) * 128 + dofs + d] = vb;
          int p = pos_l[hs][ml];
          if (p >= 0) dstk[(hbase + p) * 128 + dofs + d] = vb;
        }
      }
    }
  } else {
    int b = bm >> 10;
    float cs[4];
#pragma unroll
    for (int ni = 0; ni < 4; ni++) {
      int n = bn + wn * 64 + ni * 16 + rlo;
      float bv = bias[n];
      float sum = 0.f;
#pragma unroll
      for (int mi = 0; mi < 4; mi++)
#pragma unroll
        for (int reg = 0; reg < 4; reg++) {
          float v = acc[mi][ni][reg] + bv;
          sum += (v > 0.f ? v : 0.f);
        }
      cs[ni] = sum;
    }
#pragma unroll
    for (int ni = 0; ni < 4; ni++) {
      cs[ni] += __shfl_xor(cs[ni], 16);
      cs[ni] += __shfl_xor(cs[ni], 32);
    }
    if (lane < 16) {
#pragma unroll
      for (int ni = 0; ni < 4; ni++) {
        int n = bn + wn * 64 + ni * 16 + lane;
        atomicAdd(out + b * 1024 + n, cs[ni]);
        atomicAdd(out + 8192 + b * 1024 + n, cs[ni]);
      }
    }
  }
}

// ---------------- flash attention: QBLK=128, 8 waves, dbuf gld_lds staging ----------------
// grid 1024 (8 qtiles x 128 bh), XCD-aware decode; 512 threads.
__global__ __launch_bounds__(512) void attn_kernel(
    const bf16* __restrict__ qcat, const bf16* __restrict__ kc,
    const bf16* __restrict__ vTc, const int* __restrict__ cnt_g,
    bf16* __restrict__ ybuf) {
  __shared__ char Klds[2][64 * 256];   // 32 KB
  __shared__ char Vlds[2][64 * 128];   // 16 KB
  __shared__ char Plds[8][16 * 128];   // 16 KB
  const int id = blockIdx.x;
  const int qt = (id >> 3) & 7;
  const int bh = (id & 7) * 16 + (id >> 6);
  const int tid = threadIdx.x, lane = tid & 63, wv = tid >> 6;
  const int b = bh >> 4, hh = bh & 15;
  const int rlo = lane & 15, kgp = lane >> 4;
  const bf16* qp = qcat + (size_t)bh * 1024 * 128;
  const bf16* kp = kc + (size_t)bh * 1024 * 128;
  const bf16* vp = vTc + (size_t)bh * 64 * 1024;
  const int cnt = cnt_g[bh & 7];

  s16x8 qf[4];
  {
    int qrow = qt * 128 + wv * 16 + rlo;
#pragma unroll
    for (int kk = 0; kk < 4; kk++)
      qf[kk] = *(const s16x8*)(qp + (size_t)qrow * 128 + kk * 32 + kgp * 8);
  }

  f32x4 oacc[4];
#pragma unroll
  for (int i = 0; i < 4; i++) oacc[i] = (f32x4){0.f, 0.f, 0.f, 0.f};
  float mrun[4] = {-INFINITY, -INFINITY, -INFINITY, -INFINITY};
  float lrun[4] = {0.f, 0.f, 0.f, 0.f};
  char* pb = Plds[wv];

  auto STAGE = [&](int buf, int t0) {
#pragma unroll
    for (int r = 0; r < 2; r++) {
      int c = r * 512 + tid, row = c >> 4, sl = c & 15, gsl = sl ^ (row & 7);
      gld_lds16(kp + (size_t)(t0 + row) * 128 + gsl * 8, Klds[buf] + c * 16);
    }
    {
      int c = tid, dv = c >> 3, sl = c & 7, gsl = sl ^ (dv & 7);
      gld_lds16(vp + (size_t)dv * 1024 + t0 + gsl * 8, Vlds[buf] + c * 16);
    }
  };

  auto COMPUTE = [&](int buf, int t0) {
    char* Kb = Klds[buf];
    char* Vb = Vlds[buf];
    f32x4 sc[4];
#pragma unroll
    for (int i = 0; i < 4; i++) sc[i] = (f32x4){0.f, 0.f, 0.f, 0.f};
    __builtin_amdgcn_s_setprio(1);
#pragma unroll
    for (int kk = 0; kk < 4; kk++) {
#pragma unroll
      for (int ni = 0; ni < 4; ni++) {
        int row = ni * 16 + rlo;
        int ps = (kk * 4 + kgp) ^ (row & 7);
        s16x8 kf = *(const s16x8*)(Kb + row * 256 + ps * 16);
        sc[ni] = __builtin_amdgcn_mfma_f32_16x16x32_bf16(qf[kk], kf, sc[ni], 0, 0, 0);
      }
    }
    __builtin_amdgcn_s_setprio(0);

    const bool tail = (t0 + 64 > cnt);
    float val[4][4];
#pragma unroll
    for (int ni = 0; ni < 4; ni++) {
      bool ok = !tail || (t0 + ni * 16 + rlo) < cnt;
#pragma unroll
      for (int reg = 0; reg < 4; reg++)
        val[ni][reg] = ok ? sc[ni][reg] * 0.125f : -1e9f;
    }

    float nm[4], ex[4];
#pragma unroll
    for (int reg = 0; reg < 4; reg++) {
      float mx = fmaxf(fmaxf(val[0][reg], val[1][reg]), fmaxf(val[2][reg], val[3][reg]));
      mx = fmaxf(mx, __shfl_xor(mx, 1));
      mx = fmaxf(mx, __shfl_xor(mx, 2));
      mx = fmaxf(mx, __shfl_xor(mx, 4));
      mx = fmaxf(mx, __shfl_xor(mx, 8));
      nm[reg] = fmaxf(mrun[reg], mx);
      ex[reg] = __expf(mrun[reg] - nm[reg]);
      mrun[reg] = nm[reg];
    }
    float p[4][4];
#pragma unroll
    for (int reg = 0; reg < 4; reg++) {
      float s = 0.f;
#pragma unroll
      for (int ni = 0; ni < 4; ni++) {
        p[ni][reg] = __expf(val[ni][reg] - nm[reg]);
        s += p[ni][reg];
      }
      s += __shfl_xor(s, 1);
      s += __shfl_xor(s, 2);
      s += __shfl_xor(s, 4);
      s += __shfl_xor(s, 8);
      lrun[reg] = lrun[reg] * ex[reg] + s;
    }
#pragma unroll
    for (int n = 0; n < 4; n++)
#pragma unroll
      for (int reg = 0; reg < 4; reg++) oacc[n][reg] *= ex[reg];

#pragma unroll
    for (int ni = 0; ni < 4; ni++) {
#pragma unroll
      for (int reg = 0; reg < 4; reg++) {
        int row = kgp * 4 + reg;
        int off = row * 128 + ((ni * 32 + rlo * 2) ^ psw(row));
        *(bf16*)(pb + off) = __float2bfloat16(p[ni][reg]);
      }
    }
    asm volatile("s_waitcnt lgkmcnt(0)" ::: "memory");
    __builtin_amdgcn_sched_barrier(0);

    __builtin_amdgcn_s_setprio(1);
#pragma unroll
    for (int kk2 = 0; kk2 < 2; kk2++) {
      int poff = rlo * 128 + ((kk2 * 64 + kgp * 16) ^ psw(rlo));
      s16x8 pa = *(const s16x8*)(pb + poff);
#pragma unroll
      for (int n = 0; n < 4; n++) {
        int dv = n * 16 + rlo;
        int voff = dv * 128 + ((kk2 * 64 + kgp * 16) ^ ((dv & 7) << 4));
        s16x8 vfr = *(const s16x8*)(Vb + voff);
        oacc[n] = __builtin_amdgcn_mfma_f32_16x16x32_bf16(pa, vfr, oacc[n], 0, 0, 0);
      }
    }
    __builtin_amdgcn_s_setprio(0);
  };

  STAGE(0, 0);
  int cur = 0;
#pragma unroll 1
  for (int t0 = 0; t0 < cnt; t0 += 64) {
    asm volatile("s_waitcnt vmcnt(0)" ::: "memory");
    __syncthreads();
    if (t0 + 64 < cnt) STAGE(cur ^ 1, t0 + 64);
    COMPUTE(cur, t0);
    cur ^= 1;
  }

  int sbase = qt * 128 + wv * 16;
#pragma unroll
  for (int n = 0; n < 4; n++) {
#pragma unroll
    for (int reg = 0; reg < 4; reg++) {
      int srow = sbase + kgp * 4 + reg;
      int col = hh * 64 + n * 16 + rlo;
      float y = oacc[n][reg] / lrun[reg];
      ybuf[((size_t)b * 1024 + srow) * 1024 + col] = __float2bfloat16(y);
    }
  }
}

// ---------------- launcher ----------------
extern "C" void kernel_launch(void* const* d_in, const int* in_sizes, int n_in,
                              void* d_out, int out_size, void* d_ws, size_t ws_size,
                              hipStream_t stream) {
  const float* h = (const float*)d_in[0];
  const int* mask = (const int*)d_in[1];
  const float* l = (const float*)d_in[3];
  const float* Wq = (const float*)d_in[4];
  const float* bq = (const float*)d_in[5];
  const float* Wk = (const float*)d_in[6];
  const float* bk = (const float*)d_in[7];
  const float* Wv = (const float*)d_in[8];
  const float* bv = (const float*)d_in[9];
  const float* Wl = (const float*)d_in[12];
  const float* bl = (const float*)d_in[13];
  const float* Wo = (const float*)d_in[14];
  const float* bo = (const float*)d_in[15];
  float* out = (float*)d_out;
  char* ws = (char*)d_ws;

  bf16* hb = (bf16*)(ws + 0);                    // 16 MB (reused as ybuf)
  bf16* lb = (bf16*)(ws + 16777216);             // 2 MB
  bf16* WqkvT = (bf16*)(ws + 18874368);          // 6 MB [3072][1024]
  bf16* WoT = (bf16*)(ws + 25165824);            // 2 MB
  bf16* WlT = (bf16*)(ws + 27262976);            // 256 KB
  float* bqkv = (float*)(ws + 27525120);         // 12 KB
  bf16* qcat = (bf16*)(ws + 27537408);           // 32 MB
  bf16* kcatc = (bf16*)(ws + 61091840);          // 32 MB
  bf16* vTc = (bf16*)(ws + 94646272);            // 16 MB
  int* pos_tab = (int*)(ws + 111423488);         // 32 KB
  int* srcrow = (int*)(ws + 111456256);          // 32 KB
  int* cnt = (int*)(ws + 111489024);             // 32 B
  bf16* ybuf = hb;

  mask_scan<<<8, 64, 0, stream>>>(mask, pos_tab, srcrow, cnt);
  tail_zero<<<128, 256, 0, stream>>>(kcatc, vTc, cnt);

  cvt_f32_bf16<<<8192, 256, 0, stream>>>(h, hb, 8388608);
  cvt_f32_bf16<<<1024, 256, 0, stream>>>(l, lb, 1048576);
  dim3 tb(32, 8);
  transpose_cvt<0><<<dim3(32, 32), tb, 0, stream>>>(Wq, WqkvT, 1024, 1024, 0);
  transpose_cvt<1><<<dim3(32, 32), tb, 0, stream>>>(Wk, WqkvT, 1024, 1024, 1024);
  transpose_cvt<1><<<dim3(32, 32), tb, 0, stream>>>(Wv, WqkvT, 1024, 1024, 2048);
  transpose_cvt<0><<<dim3(32, 32), tb, 0, stream>>>(Wo, WoT, 1024, 1024, 0);
  transpose_cvt<0><<<dim3(4, 32), tb, 0, stream>>>(Wl, WlT, 128, 1024, 0);
  bias_concat<<<4, 256, 0, stream>>>(bq, bk, bv, bqkv);

  gemm_qkv<<<1536, 256, 0, stream>>>(hb, WqkvT, bqkv, srcrow, cnt,
                                     qcat, kcatc, vTc);
  gemm_bf16<0><<<dim3(64, 8), 256, 0, stream>>>(lb, WlT, bl, 128, 128, 128,
                                                qcat, kcatc, 64, pos_tab, nullptr);

  attn_kernel<<<1024, 512, 0, stream>>>(qcat, kcatc, vTc, cnt, ybuf);

  hipMemsetAsync(d_out, 0, (size_t)out_size * sizeof(float), stream);
  gemm_bf16<1><<<512, 256, 0, stream>>>(ybuf, WoT, bo, 1024, 1024, 1024,
                                        nullptr, nullptr, 0, nullptr, out);
}

// Round 10
// 204.642 us; speedup vs baseline: 1.0823x; 1.0823x over previous
//
#include <hip/hip_runtime.h>
#include <hip/hip_bf16.h>

typedef __hip_bfloat16 bf16;
typedef __attribute__((ext_vector_type(4))) float f32x4;
typedef __attribute__((ext_vector_type(8))) short s16x8;
typedef __attribute__((ext_vector_type(4))) short s16x4;

__device__ __forceinline__ void gld_lds16(const void* g, void* l) {
  __builtin_amdgcn_global_load_lds(
      (const __attribute__((address_space(1))) unsigned int*)g,
      (__attribute__((address_space(3))) unsigned int*)l, 16, 0, 0);
}

__device__ __forceinline__ short bf16bits(float f) {
  bf16 h = __float2bfloat16(f);
  return *reinterpret_cast<short*>(&h);
}

__device__ __forceinline__ int psw(int row) {
  return ((row & 7) << 4) ^ ((row & 8) << 2);
}

// K/V weight-column permutation: n=(h,d) -> r*128 + (h>>3)*64 + d, r=h&7
__device__ __forceinline__ int kvperm(int n) {
  return ((n >> 6) & 7) * 128 + (n >> 9) * 64 + (n & 63);
}

// ---------------- f32 -> bf16 elementwise convert ----------------
__global__ __launch_bounds__(256) void cvt_f32_bf16(const float* __restrict__ in,
                                                    bf16* __restrict__ out, int n) {
  int i = (blockIdx.x * 256 + threadIdx.x) * 4;
  if (i + 3 < n) {
    float4 v = *reinterpret_cast<const float4*>(in + i);
    s16x4 o;
    o[0] = bf16bits(v.x); o[1] = bf16bits(v.y);
    o[2] = bf16bits(v.z); o[3] = bf16bits(v.w);
    *reinterpret_cast<s16x4*>(out + i) = o;
  }
}

// ---------------- W (KxN f32) -> Wt (perm(N) x K bf16) ----------------
template <int PERM>
__global__ __launch_bounds__(256) void transpose_cvt(const float* __restrict__ W,
                                                     bf16* __restrict__ Wt, int K, int N,
                                                     int rowofs) {
  __shared__ float tile[32][33];
  int k0 = blockIdx.x * 32, n0 = blockIdx.y * 32;
  int tx = threadIdx.x, ty = threadIdx.y;  // block (32,8)
  for (int i = ty; i < 32; i += 8) tile[i][tx] = W[(size_t)(k0 + i) * N + n0 + tx];
  __syncthreads();
  for (int i = ty; i < 32; i += 8) {
    int nn = n0 + i;
    int orow = rowofs + (PERM ? kvperm(nn) : nn);
    Wt[(size_t)orow * K + k0 + tx] = __float2bfloat16(tile[tx][i]);
  }
}

// ---------------- bias concat (permuted for K/V groups) ----------------
__global__ __launch_bounds__(256) void bias_concat(const float* __restrict__ bq,
                                                   const float* __restrict__ bk,
                                                   const float* __restrict__ bv,
                                                   float* __restrict__ ob) {
  int n = blockIdx.x * 256 + threadIdx.x;
  if (n < 1024) {
    ob[n] = bq[n];
    int pr = kvperm(n);
    ob[1024 + pr] = bk[n];
    ob[2048 + pr] = bv[n];
  }
}

// ---------------- mask scan: pos/srcrow/cnt per pattern ----------------
__global__ __launch_bounds__(64) void mask_scan(const int* __restrict__ mask,
                                                int* __restrict__ pos_tab,
                                                int* __restrict__ srcrow,
                                                int* __restrict__ cnt) {
  int r = blockIdx.x;
  const int* mr = mask + r * 1024;
  int lane = threadIdx.x;
  int loc[16];
  int c = 0;
#pragma unroll
  for (int i = 0; i < 16; i++) {
    loc[i] = (mr[lane * 16 + i] == 0) ? 1 : 0;
    c += loc[i];
  }
  int inc = c;
#pragma unroll
  for (int off = 1; off < 64; off <<= 1) {
    int v = __shfl_up(inc, off);
    if (lane >= off) inc += v;
  }
  int running = inc - c;
#pragma unroll
  for (int i = 0; i < 16; i++) {
    pos_tab[r * 1024 + lane * 16 + i] = loc[i] ? running : -1;
    if (loc[i]) srcrow[r * 1024 + running] = lane * 16 + i;
    running += loc[i];
  }
  if (lane == 63) cnt[r] = inc;
}

// ---------------- zero-fill compacted tails [cnt, round64(cnt)) ----------------
__global__ __launch_bounds__(256) void tail_zero(bf16* __restrict__ kc,
                                                 bf16* __restrict__ vTc,
                                                 const int* __restrict__ cnt) {
  int bh = blockIdx.x;
  int c = cnt[bh & 7];
  int e = (c + 63) & ~63;
  int tid = threadIdx.x;
  bf16 z = __float2bfloat16(0.f);
  bf16* kb = kc + (size_t)bh * 1024 * 128;
  for (int i = tid; i < 64 * 128; i += 256) {
    int rr = c + (i >> 7);
    if (rr < e) kb[(size_t)rr * 128 + (i & 127)] = z;
  }
  bf16* vb = vTc + (size_t)bh * 64 * 1024;
  for (int i = tid; i < 64 * 64; i += 256) {
    int dv = i >> 6, col = c + (i & 63);
    if (col < e) vb[(size_t)dv * 1024 + col] = z;
  }
}

// ---------------- merged QKV+L GEMM (3-deep pipeline, counted vmcnt) ----------------
// grid (64, 32). y-group g = nt>>3:
//   g=0: Q (A=hb, K=1024, full M),  g=1: K-proj, g=2: V-proj (compacted gather;
//        x decode b=x&7 / basep=(x>>3)*128 keeps exit-prone tile off XCD id — R5 fix),
//   g=3: L-proj (A=lb, lda=128, K=128): dual-write qcat[...,64+d] + pos-scatter kcatc.
__global__ __launch_bounds__(256) void gemm_qkv(
    const bf16* __restrict__ A, const bf16* __restrict__ Bt,
    const bf16* __restrict__ lb, const bf16* __restrict__ WlT,
    const float* __restrict__ bias, const float* __restrict__ bl,
    const int* __restrict__ srcrow, const int* __restrict__ cnt_g,
    const int* __restrict__ pos_tab,
    bf16* __restrict__ qcat, bf16* __restrict__ kc, bf16* __restrict__ vTc) {
  __shared__ bf16 Alds[3][128 * 32];
  __shared__ bf16 Blds[3][128 * 32];
  __shared__ int pos_l[2][128];
  const int nt = blockIdx.y;
  const int g = nt >> 3;
  const int r = nt & 7;
  const int tid = threadIdx.x;
  const int lane = tid & 63, wv = tid >> 6;
  const int wm = wv >> 1, wn = wv & 1;
  const int rlo = lane & 15, kgp = lane >> 4;
  const int srow = tid >> 2, ssl = tid & 3;

  // per-group geometry
  const bf16* Ap;
  const bf16* Bp;
  int lda_, ldb_, nk;
  if (g == 3) {
    Ap = lb; lda_ = 128; nk = 4;
    Bp = WlT + (size_t)r * 128 * 128; ldb_ = 128;
  } else {
    Ap = A; lda_ = 1024; nk = 32;
    Bp = Bt + (size_t)nt * 128 * 1024; ldb_ = 1024;
  }

  int mrow0, mrow1, b = 0, basep = 0, vcnt = 128;
  if (g == 0 || g == 3) {
    int bm = blockIdx.x * 128;
    mrow0 = bm + srow;
    mrow1 = bm + 64 + srow;
    if (g == 3) {  // pos table for the two heads this tile covers
      int h0 = r * 2;
      int hs = tid >> 7, sl = tid & 127;
      pos_l[hs][sl] = pos_tab[((h0 + hs) & 7) * 1024 + (bm & 1023) + sl];
    }
  } else {
    b = blockIdx.x & 7;                 // batch: all 8 values always active
    basep = (blockIdx.x >> 3) * 128;    // exit-prone tile index, spread over XCDs
    int cr = cnt_g[r];
    if (basep >= cr) return;
    vcnt = min(128, cr - basep);
    int p0 = min(basep + srow, cr - 1);
    int p1 = min(basep + 64 + srow, cr - 1);
    mrow0 = b * 1024 + srcrow[r * 1024 + p0];
    mrow1 = b * 1024 + srcrow[r * 1024 + p1];
  }

  f32x4 acc[4][4];
#pragma unroll
  for (int i = 0; i < 4; i++)
#pragma unroll
    for (int j = 0; j < 4; j++) acc[i][j] = (f32x4){0.f, 0.f, 0.f, 0.f};

  const int gslA = ssl ^ ((srow >> 1) & 3);  // same for srow and srow+64

  auto STAGE = [&](int buf, int kt) {
    char* Ad = (char*)Alds[buf];
    char* Bd = (char*)Blds[buf];
    gld_lds16(Ap + (size_t)mrow0 * lda_ + kt + gslA * 8, Ad + tid * 16);
    gld_lds16(Ap + (size_t)mrow1 * lda_ + kt + gslA * 8, Ad + (256 + tid) * 16);
    gld_lds16(Bp + (size_t)srow * ldb_ + kt + gslA * 8, Bd + tid * 16);
    gld_lds16(Bp + (size_t)(64 + srow) * ldb_ + kt + gslA * 8, Bd + (256 + tid) * 16);
  };

  STAGE(0, 0);
  STAGE(1, 32);
  int cur = 0;
#pragma unroll 1
  for (int ti = 0; ti < nk; ti++) {
    if (ti < nk - 1) {
      asm volatile("s_waitcnt vmcnt(4)" ::: "memory");   // tile ti done; ti+1 in flight
    } else {
      asm volatile("s_waitcnt vmcnt(0)" ::: "memory");   // final tile: full drain
    }
    __syncthreads();
    if (ti + 2 < nk) {
      int b2 = cur + 2;
      if (b2 >= 3) b2 -= 3;
      STAGE(b2, (ti + 2) * 32);  // overwrites buf computed at ti-1; barrier ordered
    }

    char* Ab = (char*)Alds[cur];
    char* Bb = (char*)Blds[cur];
    s16x8 afr[4], bfr[4];
#pragma unroll
    for (int mi = 0; mi < 4; mi++) {
      int row = wm * 64 + mi * 16 + rlo;
      int ps = kgp ^ ((row >> 1) & 3);
      afr[mi] = *(const s16x8*)(Ab + row * 64 + ps * 16);
    }
#pragma unroll
    for (int ni = 0; ni < 4; ni++) {
      int row = wn * 64 + ni * 16 + rlo;
      int ps = kgp ^ ((row >> 1) & 3);
      bfr[ni] = *(const s16x8*)(Bb + row * 64 + ps * 16);
    }
#pragma unroll
    for (int mi = 0; mi < 4; mi++)
#pragma unroll
      for (int ni = 0; ni < 4; ni++)
        acc[mi][ni] = __builtin_amdgcn_mfma_f32_16x16x32_bf16(afr[mi], bfr[ni], acc[mi][ni], 0, 0, 0);
    cur = (cur == 2) ? 0 : cur + 1;
  }

  if (g == 0 || g == 3) {
#pragma unroll
    for (int mi = 0; mi < 4; mi++) {
#pragma unroll
      for (int ni = 0; ni < 4; ni++) {
        int nl = wn * 64 + ni * 16 + rlo;
        int ncol = r * 128 + nl;                 // projection-local column 0..1023
        float bv = (g == 3) ? bl[ncol] : bias[nt * 128 + nl];
        int hh = ncol >> 6, d = ncol & 63, hs = nl >> 6;
        int dof = (g == 3) ? 64 : 0;
#pragma unroll
        for (int reg = 0; reg < 4; reg++) {
          int ml = wm * 64 + mi * 16 + kgp * 4 + reg;
          int m = blockIdx.x * 128 + ml;
          int b0 = m >> 10, s = m & 1023;
          float v = acc[mi][ni][reg] + bv;
          v = v > 0.f ? v : 0.f;
          bf16 vb = __float2bfloat16(v);
          size_t hbase = (size_t)(b0 * 16 + hh) * 1024;
          qcat[(hbase + s) * 128 + dof + d] = vb;
          if (g == 3) {
            int p = pos_l[hs][ml];
            if (p >= 0) kc[(hbase + p) * 128 + 64 + d] = vb;
          }
        }
      }
    }
  } else {
#pragma unroll
    for (int mi = 0; mi < 4; mi++) {
#pragma unroll
      for (int ni = 0; ni < 4; ni++) {
        int nl = wn * 64 + ni * 16 + rlo;
        float bv = bias[nt * 128 + nl];
        int hbit = nl >> 6, d = nl & 63;
        int hh = hbit * 8 + r;
#pragma unroll
        for (int reg = 0; reg < 4; reg++) {
          int ml = wm * 64 + mi * 16 + kgp * 4 + reg;
          float v = acc[mi][ni][reg] + bv;
          v = v > 0.f ? v : 0.f;
          bf16 vb = __float2bfloat16(v);
          int p = basep + ml;
          if (ml < vcnt) {
            if (g == 1)
              kc[((size_t)(b * 16 + hh) * 1024 + p) * 128 + d] = vb;
            else
              vTc[((size_t)(b * 16 + hh) * 64 + d) * 1024 + p] = vb;
          }
        }
      }
    }
  }
}

// ---------------- O-projection GEMM: relu + column-reduce, 2-phase ----------------
__global__ __launch_bounds__(256) void gemm_oproj(
    const bf16* __restrict__ A, const bf16* __restrict__ Bt,
    const float* __restrict__ bias, float* __restrict__ out) {
  __shared__ bf16 Alds[2][128 * 32];
  __shared__ bf16 Blds[2][128 * 32];
  const int tid = threadIdx.x;
  const int lane = tid & 63, wv = tid >> 6;
  const int wm = wv >> 1, wn = wv & 1;
  const int bm = blockIdx.x * 128, bn = blockIdx.y * 128;
  const int rlo = lane & 15, kgp = lane >> 4;

  f32x4 acc[4][4];
#pragma unroll
  for (int i = 0; i < 4; i++)
#pragma unroll
    for (int j = 0; j < 4; j++) acc[i][j] = (f32x4){0.f, 0.f, 0.f, 0.f};

  const int srow = tid >> 2, ssl = tid & 3;

  auto STAGE = [&](int buf, int kt) {
    char* Ad = (char*)Alds[buf];
    char* Bd = (char*)Blds[buf];
#pragma unroll
    for (int rr = 0; rr < 2; ++rr) {
      int row = rr * 64 + srow;
      int gsl = ssl ^ ((row >> 1) & 3);
      gld_lds16(A + (size_t)(bm + row) * 1024 + kt + gsl * 8, Ad + (rr * 256 + tid) * 16);
      gld_lds16(Bt + (size_t)(bn + row) * 1024 + kt + gsl * 8, Bd + (rr * 256 + tid) * 16);
    }
  };

  STAGE(0, 0);
  int cur = 0;
#pragma unroll 1
  for (int kt = 0; kt < 1024; kt += 32) {
    asm volatile("s_waitcnt vmcnt(0)" ::: "memory");
    __syncthreads();
    if (kt + 32 < 1024) STAGE(cur ^ 1, kt + 32);

    char* Ab = (char*)Alds[cur];
    char* Bb = (char*)Blds[cur];
    s16x8 afr[4], bfr[4];
#pragma unroll
    for (int mi = 0; mi < 4; mi++) {
      int row = wm * 64 + mi * 16 + rlo;
      int ps = kgp ^ ((row >> 1) & 3);
      afr[mi] = *(const s16x8*)(Ab + row * 64 + ps * 16);
    }
#pragma unroll
    for (int ni = 0; ni < 4; ni++) {
      int row = wn * 64 + ni * 16 + rlo;
      int ps = kgp ^ ((row >> 1) & 3);
      bfr[ni] = *(const s16x8*)(Bb + row * 64 + ps * 16);
    }
#pragma unroll
    for (int mi = 0; mi < 4; mi++)
#pragma unroll
      for (int ni = 0; ni < 4; ni++)
        acc[mi][ni] = __builtin_amdgcn_mfma_f32_16x16x32_bf16(afr[mi], bfr[ni], acc[mi][ni], 0, 0, 0);
    cur ^= 1;
  }

  int b = bm >> 10;
  float cs[4];
#pragma unroll
  for (int ni = 0; ni < 4; ni++) {
    int n = bn + wn * 64 + ni * 16 + rlo;
    float bv = bias[n];
    float sum = 0.f;
#pragma unroll
    for (int mi = 0; mi < 4; mi++)
#pragma unroll
      for (int reg = 0; reg < 4; reg++) {
        float v = acc[mi][ni][reg] + bv;
        sum += (v > 0.f ? v : 0.f);
      }
    cs[ni] = sum;
  }
#pragma unroll
  for (int ni = 0; ni < 4; ni++) {
    cs[ni] += __shfl_xor(cs[ni], 16);
    cs[ni] += __shfl_xor(cs[ni], 32);
  }
  if (lane < 16) {
#pragma unroll
    for (int ni = 0; ni < 4; ni++) {
      int n = bn + wn * 64 + ni * 16 + lane;
      atomicAdd(out + b * 1024 + n, cs[ni]);
      atomicAdd(out + 8192 + b * 1024 + n, cs[ni]);
    }
  }
}

// ---------------- flash attention: QBLK=128, 8 waves, dbuf gld_lds staging ----------------
// grid 1024 (8 qtiles x 128 bh), XCD-aware decode; 512 threads.
__global__ __launch_bounds__(512) void attn_kernel(
    const bf16* __restrict__ qcat, const bf16* __restrict__ kc,
    const bf16* __restrict__ vTc, const int* __restrict__ cnt_g,
    bf16* __restrict__ ybuf) {
  __shared__ char Klds[2][64 * 256];   // 32 KB
  __shared__ char Vlds[2][64 * 128];   // 16 KB
  __shared__ char Plds[8][16 * 128];   // 16 KB
  const int id = blockIdx.x;
  const int qt = (id >> 3) & 7;
  const int bh = (id & 7) * 16 + (id >> 6);
  const int tid = threadIdx.x, lane = tid & 63, wv = tid >> 6;
  const int b = bh >> 4, hh = bh & 15;
  const int rlo = lane & 15, kgp = lane >> 4;
  const bf16* qp = qcat + (size_t)bh * 1024 * 128;
  const bf16* kp = kc + (size_t)bh * 1024 * 128;
  const bf16* vp = vTc + (size_t)bh * 64 * 1024;
  const int cnt = cnt_g[bh & 7];

  s16x8 qf[4];
  {
    int qrow = qt * 128 + wv * 16 + rlo;
#pragma unroll
    for (int kk = 0; kk < 4; kk++)
      qf[kk] = *(const s16x8*)(qp + (size_t)qrow * 128 + kk * 32 + kgp * 8);
  }

  f32x4 oacc[4];
#pragma unroll
  for (int i = 0; i < 4; i++) oacc[i] = (f32x4){0.f, 0.f, 0.f, 0.f};
  float mrun[4] = {-INFINITY, -INFINITY, -INFINITY, -INFINITY};
  float lrun[4] = {0.f, 0.f, 0.f, 0.f};
  char* pb = Plds[wv];

  auto STAGE = [&](int buf, int t0) {
#pragma unroll
    for (int r = 0; r < 2; r++) {
      int c = r * 512 + tid, row = c >> 4, sl = c & 15, gsl = sl ^ (row & 7);
      gld_lds16(kp + (size_t)(t0 + row) * 128 + gsl * 8, Klds[buf] + c * 16);
    }
    {
      int c = tid, dv = c >> 3, sl = c & 7, gsl = sl ^ (dv & 7);
      gld_lds16(vp + (size_t)dv * 1024 + t0 + gsl * 8, Vlds[buf] + c * 16);
    }
  };

  auto COMPUTE = [&](int buf, int t0) {
    char* Kb = Klds[buf];
    char* Vb = Vlds[buf];
    f32x4 sc[4];
#pragma unroll
    for (int i = 0; i < 4; i++) sc[i] = (f32x4){0.f, 0.f, 0.f, 0.f};
    __builtin_amdgcn_s_setprio(1);
#pragma unroll
    for (int kk = 0; kk < 4; kk++) {
#pragma unroll
      for (int ni = 0; ni < 4; ni++) {
        int row = ni * 16 + rlo;
        int ps = (kk * 4 + kgp) ^ (row & 7);
        s16x8 kf = *(const s16x8*)(Kb + row * 256 + ps * 16);
        sc[ni] = __builtin_amdgcn_mfma_f32_16x16x32_bf16(qf[kk], kf, sc[ni], 0, 0, 0);
      }
    }
    __builtin_amdgcn_s_setprio(0);

    const bool tail = (t0 + 64 > cnt);
    float val[4][4];
#pragma unroll
    for (int ni = 0; ni < 4; ni++) {
      bool ok = !tail || (t0 + ni * 16 + rlo) < cnt;
#pragma unroll
      for (int reg = 0; reg < 4; reg++)
        val[ni][reg] = ok ? sc[ni][reg] * 0.125f : -1e9f;
    }

    float nm[4], ex[4];
#pragma unroll
    for (int reg = 0; reg < 4; reg++) {
      float mx = fmaxf(fmaxf(val[0][reg], val[1][reg]), fmaxf(val[2][reg], val[3][reg]));
      mx = fmaxf(mx, __shfl_xor(mx, 1));
      mx = fmaxf(mx, __shfl_xor(mx, 2));
      mx = fmaxf(mx, __shfl_xor(mx, 4));
      mx = fmaxf(mx, __shfl_xor(mx, 8));
      nm[reg] = fmaxf(mrun[reg], mx);
      ex[reg] = __expf(mrun[reg] - nm[reg]);
      mrun[reg] = nm[reg];
    }
    float p[4][4];
#pragma unroll
    for (int reg = 0; reg < 4; reg++) {
      float s = 0.f;
#pragma unroll
      for (int ni = 0; ni < 4; ni++) {
        p[ni][reg] = __expf(val[ni][reg] - nm[reg]);
        s += p[ni][reg];
      }
      s += __shfl_xor(s, 1);
      s += __shfl_xor(s, 2);
      s += __shfl_xor(s, 4);
      s += __shfl_xor(s, 8);
      lrun[reg] = lrun[reg] * ex[reg] + s;
    }
#pragma unroll
    for (int n = 0; n < 4; n++)
#pragma unroll
      for (int reg = 0; reg < 4; reg++) oacc[n][reg] *= ex[reg];

#pragma unroll
    for (int ni = 0; ni < 4; ni++) {
#pragma unroll
      for (int reg = 0; reg < 4; reg++) {
        int row = kgp * 4 + reg;
        int off = row * 128 + ((ni * 32 + rlo * 2) ^ psw(row));
        *(bf16*)(pb + off) = __float2bfloat16(p[ni][reg]);
      }
    }
    asm volatile("s_waitcnt lgkmcnt(0)" ::: "memory");
    __builtin_amdgcn_sched_barrier(0);

    __builtin_amdgcn_s_setprio(1);
#pragma unroll
    for (int kk2 = 0; kk2 < 2; kk2++) {
      int poff = rlo * 128 + ((kk2 * 64 + kgp * 16) ^ psw(rlo));
      s16x8 pa = *(const s16x8*)(pb + poff);
#pragma unroll
      for (int n = 0; n < 4; n++) {
        int dv = n * 16 + rlo;
        int voff = dv * 128 + ((kk2 * 64 + kgp * 16) ^ ((dv & 7) << 4));
        s16x8 vfr = *(const s16x8*)(Vb + voff);
        oacc[n] = __builtin_amdgcn_mfma_f32_16x16x32_bf16(pa, vfr, oacc[n], 0, 0, 0);
      }
    }
    __builtin_amdgcn_s_setprio(0);
  };

  STAGE(0, 0);
  int cur = 0;
#pragma unroll 1
  for (int t0 = 0; t0 < cnt; t0 += 64) {
    asm volatile("s_waitcnt vmcnt(0)" ::: "memory");
    __syncthreads();
    if (t0 + 64 < cnt) STAGE(cur ^ 1, t0 + 64);
    COMPUTE(cur, t0);
    cur ^= 1;
  }

  int sbase = qt * 128 + wv * 16;
#pragma unroll
  for (int n = 0; n < 4; n++) {
#pragma unroll
    for (int reg = 0; reg < 4; reg++) {
      int srow = sbase + kgp * 4 + reg;
      int col = hh * 64 + n * 16 + rlo;
      float y = oacc[n][reg] / lrun[reg];
      ybuf[((size_t)b * 1024 + srow) * 1024 + col] = __float2bfloat16(y);
    }
  }
}

// ---------------- launcher ----------------
extern "C" void kernel_launch(void* const* d_in, const int* in_sizes, int n_in,
                              void* d_out, int out_size, void* d_ws, size_t ws_size,
                              hipStream_t stream) {
  const float* h = (const float*)d_in[0];
  const int* mask = (const int*)d_in[1];
  const float* l = (const float*)d_in[3];
  const float* Wq = (const float*)d_in[4];
  const float* bq = (const float*)d_in[5];
  const float* Wk = (const float*)d_in[6];
  const float* bk = (const float*)d_in[7];
  const float* Wv = (const float*)d_in[8];
  const float* bv = (const float*)d_in[9];
  const float* Wl = (const float*)d_in[12];
  const float* bl = (const float*)d_in[13];
  const float* Wo = (const float*)d_in[14];
  const float* bo = (const float*)d_in[15];
  float* out = (float*)d_out;
  char* ws = (char*)d_ws;

  bf16* hb = (bf16*)(ws + 0);                    // 16 MB (reused as ybuf)
  bf16* lb = (bf16*)(ws + 16777216);             // 2 MB
  bf16* WqkvT = (bf16*)(ws + 18874368);          // 6 MB [3072][1024]
  bf16* WoT = (bf16*)(ws + 25165824);            // 2 MB
  bf16* WlT = (bf16*)(ws + 27262976);            // 256 KB
  float* bqkv = (float*)(ws + 27525120);         // 12 KB
  bf16* qcat = (bf16*)(ws + 27537408);           // 32 MB
  bf16* kcatc = (bf16*)(ws + 61091840);          // 32 MB
  bf16* vTc = (bf16*)(ws + 94646272);            // 16 MB
  int* pos_tab = (int*)(ws + 111423488);         // 32 KB
  int* srcrow = (int*)(ws + 111456256);          // 32 KB
  int* cnt = (int*)(ws + 111489024);             // 32 B
  bf16* ybuf = hb;

  mask_scan<<<8, 64, 0, stream>>>(mask, pos_tab, srcrow, cnt);
  tail_zero<<<128, 256, 0, stream>>>(kcatc, vTc, cnt);

  cvt_f32_bf16<<<8192, 256, 0, stream>>>(h, hb, 8388608);
  cvt_f32_bf16<<<1024, 256, 0, stream>>>(l, lb, 1048576);
  dim3 tb(32, 8);
  transpose_cvt<0><<<dim3(32, 32), tb, 0, stream>>>(Wq, WqkvT, 1024, 1024, 0);
  transpose_cvt<1><<<dim3(32, 32), tb, 0, stream>>>(Wk, WqkvT, 1024, 1024, 1024);
  transpose_cvt<1><<<dim3(32, 32), tb, 0, stream>>>(Wv, WqkvT, 1024, 1024, 2048);
  transpose_cvt<0><<<dim3(32, 32), tb, 0, stream>>>(Wo, WoT, 1024, 1024, 0);
  transpose_cvt<0><<<dim3(4, 32), tb, 0, stream>>>(Wl, WlT, 128, 1024, 0);
  bias_concat<<<4, 256, 0, stream>>>(bq, bk, bv, bqkv);

  gemm_qkv<<<dim3(64, 32), 256, 0, stream>>>(hb, WqkvT, lb, WlT, bqkv, bl,
                                             srcrow, cnt, pos_tab,
                                             qcat, kcatc, vTc);

  attn_kernel<<<1024, 512, 0, stream>>>(qcat, kcatc, vTc, cnt, ybuf);

  hipMemsetAsync(d_out, 0, (size_t)out_size * sizeof(float), stream);
  gemm_oproj<<<dim3(64, 8), 256, 0, stream>>>(ybuf, WoT, bo, out);
}